// Round 2
// baseline (312.190 us; speedup 1.0000x reference)
//
#include <hip/hip_runtime.h>

#define CUT 512
#define HH 4096
#define WW 4096
#define SPAN 2048        // max input span per 256-wide output tile: 255*8+2 = 2042
#define NIMG 13          // z=0 overview (writes 4 outputs), z=1..12 inner crops

// XOR swizzle to break stride-8 LDS bank conflicts (store stays conflict-free;
// stride-8 gather becomes 2-way which is free per m136).
__device__ __forceinline__ int sw(int x) { return x ^ ((x >> 5) & 31); }

// Reference-exact coordinate math:
//   t = ((i+0.5)*s)/512 - 0.5 ; v = clip(off+t, off, off+s-1)
//   c0 = floor(v) ; c1 = min(c0+1, off+size-1) ; w = v - c0
__device__ __forceinline__ void coord(int i, int off, int size, float s,
                                      int& c0, int& c1, float& w) {
    float t = ((i + 0.5f) * s) / 512.0f - 0.5f;
    float offf = (float)off;
    float v = off + t;
    v = fminf(fmaxf(v, offf), offf + s - 1.0f);
    c0 = (int)floorf(v);
    c1 = min(c0 + 1, off + size - 1);
    w = v - (float)c0;
}

__global__ __launch_bounds__(256)
void cutouts_kernel(const float* __restrict__ img,
                    const int* __restrict__ sizes,
                    const int* __restrict__ offy,
                    const int* __restrict__ offx,
                    float* __restrict__ out) {
    __shared__ float rows[3][2][SPAN];   // 48 KB

    const int z   = blockIdx.z;          // 0 = overview, 1..12 = crop z-1
    const int i   = blockIdx.y;          // output row
    const int jt  = blockIdx.x * 256;    // tile x base
    const int tid = threadIdx.x;
    const int j   = jt + tid;            // output x

    int size, oy, ox;
    if (z == 0) { size = 4096; oy = 0; ox = 0; }
    else        { size = sizes[z - 1]; oy = offy[z - 1]; ox = offx[z - 1]; }
    const float s = (float)size;

    // Row coordinates (uniform across block)
    int y0, y1; float wy;
    coord(i, oy, size, s, y0, y1, wy);

    // Input x-span covering all taps of this tile (coord is monotone in j)
    int xlo, xhi, dmy; float wd;
    coord(jt,       ox, size, s, xlo, dmy, wd);
    coord(jt + 255, ox, size, s, dmy, xhi, wd);
    const int span = xhi - xlo + 1;      // <= 2042

    // Coalesced staging: 2 rows x 3 channels over [xlo, xhi]
    const float* r00 = img + (size_t)0 * HH * WW + (size_t)y0 * WW + xlo;
    const float* r01 = img + (size_t)0 * HH * WW + (size_t)y1 * WW + xlo;
    const float* r10 = img + (size_t)1 * HH * WW + (size_t)y0 * WW + xlo;
    const float* r11 = img + (size_t)1 * HH * WW + (size_t)y1 * WW + xlo;
    const float* r20 = img + (size_t)2 * HH * WW + (size_t)y0 * WW + xlo;
    const float* r21 = img + (size_t)2 * HH * WW + (size_t)y1 * WW + xlo;

    for (int idx = tid; idx < span; idx += 256) {
        int si = sw(idx);
        rows[0][0][si] = r00[idx];
        rows[0][1][si] = r01[idx];
        rows[1][0][si] = r10[idx];
        rows[1][1][si] = r11[idx];
        rows[2][0][si] = r20[idx];
        rows[2][1][si] = r21[idx];
    }
    __syncthreads();

    // Per-thread x taps
    int x0, x1; float wx;
    coord(j, ox, size, s, x0, x1, wx);
    const int l0 = sw(x0 - xlo);
    const int l1 = sw(x1 - xlo);

    float v[3];
#pragma unroll
    for (int c = 0; c < 3; ++c) {
        float a = rows[c][0][l0];
        float b = rows[c][0][l1];
        float cc = rows[c][1][l0];
        float d = rows[c][1][l1];
        float top = a * (1.0f - wx) + b * wx;
        float bot = cc * (1.0f - wx) + d * wx;
        v[c] = top * (1.0f - wy) + bot * wy;
    }

    const size_t imgStride = (size_t)3 * CUT * CUT;
    const size_t chStride  = (size_t)CUT * CUT;
    const size_t px  = (size_t)i * CUT + j;

    if (z == 0) {
        float gray = v[0] * 0.2989f + v[1] * 0.587f + v[2] * 0.114f;
        const size_t pxf = (size_t)i * CUT + (CUT - 1 - j);
#pragma unroll
        for (int c = 0; c < 3; ++c) {
            out[0 * imgStride + c * chStride + px]  = v[c];
            out[1 * imgStride + c * chStride + px]  = gray;
            out[2 * imgStride + c * chStride + pxf] = v[c];
            out[3 * imgStride + c * chStride + pxf] = gray;
        }
    } else {
        const int k = z - 1;
        const size_t base = (size_t)(4 + k) * imgStride;
        if (k == 0) {
            float gray = v[0] * 0.2989f + v[1] * 0.587f + v[2] * 0.114f;
#pragma unroll
            for (int c = 0; c < 3; ++c)
                out[base + c * chStride + px] = gray;
        } else {
#pragma unroll
            for (int c = 0; c < 3; ++c)
                out[base + c * chStride + px] = v[c];
        }
    }
}

extern "C" void kernel_launch(void* const* d_in, const int* in_sizes, int n_in,
                              void* d_out, int out_size, void* d_ws, size_t ws_size,
                              hipStream_t stream) {
    const float* img  = (const float*)d_in[0];
    // d_in[1] = t (unused by the reference)
    const int* sizes  = (const int*)d_in[2];
    const int* offy   = (const int*)d_in[3];
    const int* offx   = (const int*)d_in[4];
    float* out = (float*)d_out;

    dim3 block(256, 1, 1);
    dim3 grid(CUT / 256, CUT, NIMG);   // (2, 512, 13)
    hipLaunchKernelGGL(cutouts_kernel, grid, block, 0, stream,
                       img, sizes, offy, offx, out);
}